// Round 1
// 1287.056 us; speedup vs baseline: 1.0241x; 1.0241x over previous
//
#include <hip/hip_runtime.h>
#include <math.h>

typedef __bf16 bf16;
typedef __bf16 bf16x8 __attribute__((ext_vector_type(8)));
typedef __bf16 bf16x4 __attribute__((ext_vector_type(4)));
typedef float f32x4 __attribute__((ext_vector_type(4)));

#define NROW 8192
#define BHALF 4096
#define DFE 2048
#define DP 256
#define NCLS 1000

#define LOGITS_N 8191
#define OUT_LOGITS 2
#define OUT_LABELS (2 + 8192 * 8191)
#define OUT_LIDS32 (OUT_LABELS + 8192)
#define OUT_LIDS512 (OUT_LIDS32 + 8192)

#define G0TILES 1056  // mode-0: 256x128 tiles covering upper triangle (j >= 2i), 32 row-tiles x 64 col-tiles
#define G1TILES 2048  // mode-1: 32 x 64 full grid (logits)

// async 16B global->LDS (dest = wave-uniform base + lane*16)
__device__ inline void gload16(const bf16* g, bf16* l) {
    __builtin_amdgcn_global_load_lds((const __attribute__((address_space(1))) void*)g,
                                     (__attribute__((address_space(3))) void*)l, 16, 0, 0);
}

// ---------------- init: zero scalar accumulators + write labels ----------------
__global__ __launch_bounds__(256) void init_kernel(float* out) {
    int i = blockIdx.x * 256 + threadIdx.x;
    if (i < 2) out[i] = 0.f;
    if (i < NROW) out[(size_t)OUT_LABELS + i] = (float)(i & (BHALF - 1));
}

// ---------------- split fe into bf16 hi/lo + row norms ----------------
__global__ __launch_bounds__(256) void split_fe_kernel(const float* __restrict__ fe0,
                                                       const float* __restrict__ fe1,
                                                       bf16* __restrict__ feh,
                                                       bf16* __restrict__ fel,
                                                       float* __restrict__ norms) {
    int row = blockIdx.x, tid = threadIdx.x;
    const float* src = (row < BHALF) ? fe0 + (size_t)row * DFE
                                     : fe1 + (size_t)(row - BHALF) * DFE;
    float ss = 0.f;
#pragma unroll
    for (int pass = 0; pass < 2; ++pass) {
        int c = (pass * 256 + tid) * 4;
        float4 v = *(const float4*)(src + c);
        ss += v.x * v.x + v.y * v.y + v.z * v.z + v.w * v.w;
        bf16 h0 = (bf16)v.x, h1 = (bf16)v.y, h2 = (bf16)v.z, h3 = (bf16)v.w;
        bf16 l0 = (bf16)(v.x - (float)h0), l1 = (bf16)(v.y - (float)h1);
        bf16 l2 = (bf16)(v.z - (float)h2), l3 = (bf16)(v.w - (float)h3);
        bf16x4 hv = {h0, h1, h2, h3};
        bf16x4 lv = {l0, l1, l2, l3};
        *(bf16x4*)(feh + (size_t)row * DFE + c) = hv;
        *(bf16x4*)(fel + (size_t)row * DFE + c) = lv;
    }
#pragma unroll
    for (int off = 32; off; off >>= 1) ss += __shfl_down(ss, off);
    __shared__ float red[4];
    if ((tid & 63) == 0) red[tid >> 6] = ss;
    __syncthreads();
    if (tid == 0) norms[row] = red[0] + red[1] + red[2] + red[3];
}

// ---------------- l2-normalize p -> bf16 (HH-only logits path) ----------------
__global__ __launch_bounds__(256) void norm_split_p_kernel(const float* __restrict__ p0,
                                                           const float* __restrict__ p1,
                                                           bf16* __restrict__ oh) {
    int row = blockIdx.x, tid = threadIdx.x;
    const float* src = (row < BHALF) ? p0 + (size_t)row * DP
                                     : p1 + (size_t)(row - BHALF) * DP;
    float x = src[tid];
    float ss = x * x;
#pragma unroll
    for (int off = 32; off; off >>= 1) ss += __shfl_down(ss, off);
    __shared__ float red[4];
    if ((tid & 63) == 0) red[tid >> 6] = ss;
    __syncthreads();
    float tot = red[0] + red[1] + red[2] + red[3];
    float rn = 1.f / fmaxf(sqrtf(tot), 1e-12f);
    oh[(size_t)row * DP + tid] = (bf16)(x * rn);
}

// ---------------- BYOL main loss ----------------
__device__ inline float dot4(float4 a, float4 b) {
    return a.x * b.x + a.y * b.y + a.z * b.z + a.w * b.w;
}

__global__ __launch_bounds__(256) void byol_kernel(const float* __restrict__ p0,
                                                   const float* __restrict__ p1,
                                                   const float* __restrict__ z0,
                                                   const float* __restrict__ z1,
                                                   float* out) {
    int tid = threadIdx.x, wave = tid >> 6, lane = tid & 63;
    int row = blockIdx.x * 4 + wave;
    size_t base = (size_t)row * DP + lane * 4;
    float4 a0 = *(const float4*)(p0 + base);
    float4 b0 = *(const float4*)(z1 + base);
    float4 a1 = *(const float4*)(p1 + base);
    float4 b1 = *(const float4*)(z0 + base);
    float pp0 = dot4(a0, a0), zz0 = dot4(b0, b0), pz0 = dot4(a0, b0);
    float pp1 = dot4(a1, a1), zz1 = dot4(b1, b1), pz1 = dot4(a1, b1);
#pragma unroll
    for (int off = 32; off; off >>= 1) {
        pp0 += __shfl_down(pp0, off); zz0 += __shfl_down(zz0, off); pz0 += __shfl_down(pz0, off);
        pp1 += __shfl_down(pp1, off); zz1 += __shfl_down(zz1, off); pz1 += __shfl_down(pz1, off);
    }
    __shared__ float red[4];
    if (lane == 0) {
        float c0 = pz0 / (fmaxf(sqrtf(pp0), 1e-12f) * fmaxf(sqrtf(zz0), 1e-12f));
        float c1 = pz1 / (fmaxf(sqrtf(pp1), 1e-12f) * fmaxf(sqrtf(zz1), 1e-12f));
        red[wave] = (2.f - 2.f * c0) + (2.f - 2.f * c1);
    }
    __syncthreads();
    if (tid == 0) atomicAdd(out, (red[0] + red[1] + red[2] + red[3]) * (1.f / 4096.f));
}

// ---------------- online linear-probe CE loss ----------------
__global__ __launch_bounds__(256) void online_kernel(const float* __restrict__ cls0,
                                                     const float* __restrict__ cls1,
                                                     const int* __restrict__ labels,
                                                     float* out) {
    int tid = threadIdx.x, wave = tid >> 6, lane = tid & 63;
    int row = blockIdx.x * 4 + wave;
    const float* src = (row < BHALF) ? cls0 + (size_t)row * NCLS
                                     : cls1 + (size_t)(row - BHALF) * NCLS;
    int lbl = labels[row & (BHALF - 1)];
    float xs[16];
    float mx = -INFINITY;
#pragma unroll
    for (int j = 0; j < 16; ++j) {
        int c = lane + j * 64;
        xs[j] = (c < NCLS) ? src[c] : -INFINITY;
        mx = fmaxf(mx, xs[j]);
    }
#pragma unroll
    for (int off = 32; off; off >>= 1) mx = fmaxf(mx, __shfl_xor(mx, off));
    float se = 0.f;
#pragma unroll
    for (int j = 0; j < 16; ++j) se += expf(xs[j] - mx);
#pragma unroll
    for (int off = 32; off; off >>= 1) se += __shfl_xor(se, off);
    __shared__ float red[4];
    if (lane == 0) red[wave] = src[lbl] - mx - logf(se);
    __syncthreads();
    if (tid == 0) atomicAdd(out + 1, -(red[0] + red[1] + red[2] + red[3]) * (1.f / 8192.f));
}

// ---------------- merged 256x128-tile pipelined GEMM (mode0: d2, mode1: logits) ----------------
// 8 waves (WM=4 x WN=2), per-wave 64x64 output (4x4 frags of 16x16x32 bf16 MFMA).
// 2 phases per 64-wide K-tile (A-lo / A-hi); B frags register-resident across both.
// LDS per buffer: A 256x64 (32KB) + B 128x64 (16KB); 2 buffers = 96KB -> 1 block/CU.
// Staging runs 2 phases ahead: phase0(t) stages A-hi(t+1) into buf[t+1];
// phase1(t) stages A-lo/B(t+2) into buf[t] regions already consumed this tile.
// Counted s_waitcnt vmcnt(6) at every phase boundary (never 0 in steady state).
// Same XOR-swizzle as verified kernel: LDS[row][phys_grp] holds logical grp^(row&7).
__device__ inline void stage_half(const bf16* __restrict__ mat, int Kd, int rowbase,
                                  int k0, bf16* lds, int wave, int rsub, int lg) {
#pragma unroll
    for (int q = 0; q < 2; ++q)
        gload16(mat + (size_t)(rowbase + q * 64 + wave * 8 + rsub) * Kd + k0 + lg * 8,
                lds + (q * 64 + wave * 8) * 64);
}

__global__ __launch_bounds__(512, 2) void gemm_kernel(const bf16* __restrict__ Hp,
                                                      const bf16* __restrict__ Lp,
                                                      const bf16* __restrict__ OHp,
                                                      const float* __restrict__ norms,
                                                      float* __restrict__ d2,
                                                      float* __restrict__ outlog) {
    __shared__ bf16 sm[2][24576];  // per buf: A[256][64] @0, B[128][64] @16384 elts
    int tid = threadIdx.x, lane = tid & 63, wave = tid >> 6;
    int wr = wave >> 1, wc = wave & 1;
    int lrow = lane & 15, lquad = lane >> 4, r7 = lrow & 7, pg = lquad ^ r7;
    int rsub = lane >> 3, grp = lane & 7, lg = grp ^ rsub;

    int bid = blockIdx.x;
    int mode, tm, tn, ksh;
    const bf16 *Hmat, *Lmat;
    int Kd;
    if (bid < G0TILES) {
        mode = 0;
        // XCD-bijective swizzle (1056 % 8 == 0)
        int sw = (bid & 7) * (G0TILES / 8) + (bid >> 3);
        int i = 0;
        while ((i + 1) * (65 - (i + 1)) <= sw) ++i;  // prefix(i) = i*(65-i)
        tm = i;
        tn = 2 * i + (sw - i * (65 - i));
        Hmat = Hp; Lmat = Lp; Kd = DFE; ksh = 5;
    } else {
        mode = 1;
        int id = bid - G0TILES;
        int sw = (id & 7) * (G1TILES / 8) + (id >> 3);
        tm = sw & 31; tn = sw >> 5;
        Hmat = OHp; Lmat = OHp; Kd = DP; ksh = 2;
    }
    int NT = (mode == 0 ? 3 : 1) << ksh;  // chunks * K/64
    int kmask = (1 << ksh) - 1;
    int arow0 = tm * 256, brow0 = tn * 128;

    f32x4 acc[4][4];
    f32x4 zz = {0.f, 0.f, 0.f, 0.f};
#pragma unroll
    for (int i = 0; i < 4; ++i)
#pragma unroll
        for (int j = 0; j < 4; ++j) acc[i][j] = zz;

    // prologue: [A-lo(0),B(0)] [A-hi(0)] [A-lo(1),B(1)] -> 10 loads; keep last 6 in flight
    stage_half(Hmat, Kd, arow0, 0, sm[0], wave, rsub, lg);
    stage_half(Hmat, Kd, brow0, 0, sm[0] + 16384, wave, rsub, lg);
    stage_half(Hmat, Kd, arow0 + 128, 0, sm[0] + 8192, wave, rsub, lg);
    stage_half(Hmat, Kd, arow0, 64, sm[1], wave, rsub, lg);
    stage_half(Hmat, Kd, brow0, 64, sm[1] + 16384, wave, rsub, lg);
    asm volatile("s_waitcnt vmcnt(6)" ::: "memory");
    __builtin_amdgcn_s_barrier();

    bf16x8 bfr[4][2];
    for (int gt = 0; gt < NT; ++gt) {
        int cur = gt & 1;
        const char* Sb = (const char*)sm[cur];
        // staging sources for tiles gt+1 (A-hi) and gt+2 (A-lo + B)
        const bf16 *A1m = Hmat, *A2m = Hmat, *B2m = Hmat;
        int k01 = 0, k02 = 0;
        if (gt + 1 < NT) {
            int nt = gt + 1, ch = nt >> ksh;
            k01 = (nt & kmask) * 64;
            A1m = (ch == 1) ? Lmat : Hmat;
        }
        if (gt + 2 < NT) {
            int nt = gt + 2, ch = nt >> ksh;
            k02 = (nt & kmask) * 64;
            A2m = (ch == 1) ? Lmat : Hmat;
            B2m = (ch == 2) ? Lmat : Hmat;
        }

        // ---------------- phase 0: A-lo frags + all B frags ----------------
        bf16x8 af[2][2];
#pragma unroll
        for (int ii = 0; ii < 2; ++ii) {
            int off = ((ii * 4 + wr) * 16 + lrow) * 128 + pg * 16;
            af[ii][0] = *(const bf16x8*)(Sb + off);
            af[ii][1] = *(const bf16x8*)(Sb + (off ^ 64));
        }
#pragma unroll
        for (int j = 0; j < 4; ++j) {
            int off = 32768 + ((j * 2 + wc) * 16 + lrow) * 128 + pg * 16;
            bfr[j][0] = *(const bf16x8*)(Sb + off);
            bfr[j][1] = *(const bf16x8*)(Sb + (off ^ 64));
        }
        if (gt + 1 < NT)
            stage_half(A1m, Kd, arow0 + 128, k01, sm[cur ^ 1] + 8192, wave, rsub, lg);
        __builtin_amdgcn_s_barrier();
        asm volatile("s_waitcnt lgkmcnt(0)" ::: "memory");
        __builtin_amdgcn_sched_barrier(0);
        __builtin_amdgcn_s_setprio(1);
#pragma unroll
        for (int ii = 0; ii < 2; ++ii)
#pragma unroll
            for (int j = 0; j < 4; ++j) {
                acc[ii][j] = __builtin_amdgcn_mfma_f32_16x16x32_bf16(af[ii][0], bfr[j][0], acc[ii][j], 0, 0, 0);
                acc[ii][j] = __builtin_amdgcn_mfma_f32_16x16x32_bf16(af[ii][1], bfr[j][1], acc[ii][j], 0, 0, 0);
            }
        __builtin_amdgcn_s_setprio(0);
        if (gt + 1 < NT) asm volatile("s_waitcnt vmcnt(6)" ::: "memory");
        else             asm volatile("s_waitcnt vmcnt(0)" ::: "memory");
        __builtin_amdgcn_s_barrier();

        // ---------------- phase 1: A-hi frags (B reused from registers) ----------------
#pragma unroll
        for (int ii = 0; ii < 2; ++ii) {
            int off = (((ii + 2) * 4 + wr) * 16 + lrow) * 128 + pg * 16;
            af[ii][0] = *(const bf16x8*)(Sb + off);
            af[ii][1] = *(const bf16x8*)(Sb + (off ^ 64));
        }
        if (gt + 2 < NT) {
            stage_half(A2m, Kd, arow0, k02, sm[cur], wave, rsub, lg);
            stage_half(B2m, Kd, brow0, k02, sm[cur] + 16384, wave, rsub, lg);
        }
        __builtin_amdgcn_s_barrier();
        asm volatile("s_waitcnt lgkmcnt(0)" ::: "memory");
        __builtin_amdgcn_sched_barrier(0);
        __builtin_amdgcn_s_setprio(1);
#pragma unroll
        for (int ii = 0; ii < 2; ++ii)
#pragma unroll
            for (int j = 0; j < 4; ++j) {
                acc[ii + 2][j] = __builtin_amdgcn_mfma_f32_16x16x32_bf16(af[ii][0], bfr[j][0], acc[ii + 2][j], 0, 0, 0);
                acc[ii + 2][j] = __builtin_amdgcn_mfma_f32_16x16x32_bf16(af[ii][1], bfr[j][1], acc[ii + 2][j], 0, 0, 0);
            }
        __builtin_amdgcn_s_setprio(0);
        if (gt + 2 < NT)      asm volatile("s_waitcnt vmcnt(6)" ::: "memory");
        else if (gt + 1 < NT) asm volatile("s_waitcnt vmcnt(2)" ::: "memory");
        __builtin_amdgcn_s_barrier();
    }

    // ---------------- epilogue ----------------
    if (mode == 0) {
#pragma unroll
        for (int i = 0; i < 4; ++i) {
#pragma unroll
            for (int e = 0; e < 4; ++e) {
                int grow = arow0 + (i * 4 + wr) * 16 + lquad * 4 + e;
                float na = norms[grow];
#pragma unroll
                for (int j = 0; j < 4; ++j) {
                    int gcol = tn * 128 + (j * 2 + wc) * 16 + lrow;
                    float v = na + norms[gcol] - 2.f * acc[i][j][e];
                    d2[(size_t)grow * NROW + gcol] = fmaxf(v, 0.f);
                }
            }
        }
    } else {
#pragma unroll
        for (int i = 0; i < 4; ++i) {
#pragma unroll
            for (int j = 0; j < 4; ++j) {
#pragma unroll
                for (int e = 0; e < 4; ++e) {
                    int r = arow0 + (i * 4 + wr) * 16 + lquad * 4 + e;
                    int c = tn * 128 + (j * 2 + wc) * 16 + lrow;
                    int oc = 0;
                    bool skip = false;
                    if (r < BHALF) {
                        if (c >= BHALF) oc = c - BHALF;           // l01 block
                        else if (c == r) skip = true;             // diag of l00
                        else oc = BHALF + (c < r ? c : c - 1);    // l00 nodiag
                    } else {
                        int rp = r - BHALF;
                        if (c < BHALF) oc = c;                    // l10 block
                        else {
                            int cp = c - BHALF;
                            if (cp == rp) skip = true;            // diag of l11
                            else oc = BHALF + (cp < rp ? cp : cp - 1);
                        }
                    }
                    if (!skip) outlog[(size_t)r * LOGITS_N + oc] = acc[i][j][e];
                }
            }
        }
    }
}

// ---------------- mirror upper triangle of D2 into lower ----------------
__global__ __launch_bounds__(256) void mirror_kernel(float* __restrict__ d2) {
    int bj = blockIdx.x, bi = blockIdx.y;
    if (bi < bj) return;  // only lower-left (incl diagonal) blocks write
    __shared__ float t[32][33];
    int tx = threadIdx.x & 31, ty = threadIdx.x >> 5;  // 32 x 8
#pragma unroll
    for (int r = 0; r < 32; r += 8)
        t[r + ty][tx] = d2[(size_t)(bj * 32 + r + ty) * NROW + bi * 32 + tx];
    __syncthreads();
#pragma unroll
    for (int r = 0; r < 32; r += 8) {
        int gi = bi * 32 + r + ty, gj = bj * 32 + tx;
        if (gi > gj) d2[(size_t)gi * NROW + gj] = t[tx][r + ty];
    }
}

// ---------------- wave-per-row exact rank-32 / rank-512 select + LID ----------------
// 128 values/lane in VGPRs, no block barriers; common-prefix skip via AND/OR reduce.
__global__ __launch_bounds__(256) void select_kernel(const float* __restrict__ d2,
                                                     float* __restrict__ out) {
    int wave = threadIdx.x >> 6, lane = threadIdx.x & 63;
    int row = blockIdx.x * 4 + wave;
    const float4* drow4 = (const float4*)(d2 + (size_t)row * NROW);
    unsigned v[128];
    unsigned andv = 0xFFFFFFFFu, orv = 0u;
#pragma unroll
    for (int j = 0; j < 32; ++j) {
        int idx4 = j * 64 + lane;
        float4 f = drow4[idx4];
        int c0 = idx4 * 4;
        unsigned u0 = __float_as_uint(f.x), u1 = __float_as_uint(f.y);
        unsigned u2 = __float_as_uint(f.z), u3 = __float_as_uint(f.w);
        bool s0 = (c0 == row), s1 = (c0 + 1 == row), s2 = (c0 + 2 == row), s3 = (c0 + 3 == row);
        v[j * 4 + 0] = s0 ? 0xFFFFFFFFu : u0;
        v[j * 4 + 1] = s1 ? 0xFFFFFFFFu : u1;
        v[j * 4 + 2] = s2 ? 0xFFFFFFFFu : u2;
        v[j * 4 + 3] = s3 ? 0xFFFFFFFFu : u3;
        andv &= (s0 ? 0xFFFFFFFFu : u0); orv |= (s0 ? 0u : u0);
        andv &= (s1 ? 0xFFFFFFFFu : u1); orv |= (s1 ? 0u : u1);
        andv &= (s2 ? 0xFFFFFFFFu : u2); orv |= (s2 ? 0u : u2);
        andv &= (s3 ? 0xFFFFFFFFu : u3); orv |= (s3 ? 0u : u3);
    }
#pragma unroll
    for (int off = 32; off; off >>= 1) {
        andv &= __shfl_xor(andv, off);
        orv |= __shfl_xor(orv, off);
    }
    unsigned diff = andv ^ orv;
    int msb = 31 - __clz((int)(diff | 1u));
    unsigned common = (msb == 31) ? 0u : (andv & (0xFFFFFFFFu << (msb + 1)));
    unsigned p1 = common, p2 = common;
    for (int bit = msb; bit >= 0; --bit) {
        unsigned c1 = p1 | (1u << bit), c2 = p2 | (1u << bit);
        unsigned n1 = 0, n2 = 0;
#pragma unroll
        for (int j = 0; j < 128; ++j) { n1 += (v[j] < c1); n2 += (v[j] < c2); }
#pragma unroll
        for (int off = 32; off; off >>= 1) {
            n1 += __shfl_xor(n1, off);
            n2 += __shfl_xor(n2, off);
        }
        if (n1 < 32u) p1 = c1;
        if (n2 < 512u) p2 = c2;
    }
    float dk1 = sqrtf(__uint_as_float(p1));
    float dk2 = sqrtf(__uint_as_float(p2));
    float s1 = 0.f, s2 = 0.f;
#pragma unroll
    for (int j = 0; j < 128; ++j) {
        unsigned b = v[j];
        if (b < p2) {
            float d = sqrtf(__uint_as_float(b));
            s2 += logf(d / dk2 + 1e-12f);
            if (b < p1) s1 += logf(d / dk1 + 1e-12f);
        }
    }
#pragma unroll
    for (int off = 32; off; off >>= 1) {
        s1 += __shfl_xor(s1, off);
        s2 += __shfl_xor(s2, off);
    }
    if (lane == 0) {
        out[(size_t)OUT_LIDS32 + row] = -32.f / s1;
        out[(size_t)OUT_LIDS512 + row] = -512.f / s2;
    }
}

extern "C" void kernel_launch(void* const* d_in, const int* in_sizes, int n_in,
                              void* d_out, int out_size, void* d_ws, size_t ws_size,
                              hipStream_t stream) {
    const float* fe0 = (const float*)d_in[0];
    const float* fe1 = (const float*)d_in[1];
    const float* p0 = (const float*)d_in[2];
    const float* p1 = (const float*)d_in[3];
    const float* z0 = (const float*)d_in[4];
    const float* z1 = (const float*)d_in[5];
    const float* cls0 = (const float*)d_in[6];
    const float* cls1 = (const float*)d_in[7];
    const int* labels = (const int*)d_in[8];
    float* out = (float*)d_out;

    // workspace layout
    char* ws = (char*)d_ws;
    float* D2 = (float*)ws;                                        // 268435456 B
    bf16* FEH = (bf16*)(ws + 268435456UL);                         // 33554432 B
    bf16* FEL = (bf16*)(ws + 268435456UL + 33554432UL);            // 33554432 B
    bf16* OH = (bf16*)(ws + 268435456UL + 2 * 33554432UL);         // 4194304 B
    float* NORMS = (float*)(ws + 268435456UL + 2 * 33554432UL + 4194304UL);  // 32 KB

    init_kernel<<<32, 256, 0, stream>>>(out);
    split_fe_kernel<<<8192, 256, 0, stream>>>(fe0, fe1, FEH, FEL, NORMS);
    norm_split_p_kernel<<<8192, 256, 0, stream>>>(p0, p1, OH);
    byol_kernel<<<1024, 256, 0, stream>>>(p0, p1, z0, z1, out);
    online_kernel<<<2048, 256, 0, stream>>>(cls0, cls1, labels, out);
    // merged GEMM: blocks [0,1056) = d2 triangle tiles, [1056,3104) = logits tiles
    // (logits tiles fill the makespan tail of the long d2 blocks)
    gemm_kernel<<<G0TILES + G1TILES, 512, 0, stream>>>(FEH, FEL, OH, NORMS, D2, out + OUT_LOGITS);
    mirror_kernel<<<dim3(256, 256), 256, 0, stream>>>(D2);
    select_kernel<<<2048, 256, 0, stream>>>(D2, out);
}

// Round 2
// 1252.087 us; speedup vs baseline: 1.0527x; 1.0279x over previous
//
#include <hip/hip_runtime.h>
#include <math.h>

typedef __bf16 bf16;
typedef __bf16 bf16x8 __attribute__((ext_vector_type(8)));
typedef __bf16 bf16x4 __attribute__((ext_vector_type(4)));
typedef float f32x4 __attribute__((ext_vector_type(4)));

#define NROW 8192
#define BHALF 4096
#define DFE 2048
#define DP 256
#define NCLS 1000

#define LOGITS_N 8191
#define OUT_LOGITS 2
#define OUT_LABELS (2 + 8192 * 8191)
#define OUT_LIDS32 (OUT_LABELS + 8192)
#define OUT_LIDS512 (OUT_LIDS32 + 8192)

#define G0TILES 1056  // mode-0: 256x128 tiles covering upper triangle (j >= 2i)
#define G1TILES 2048  // mode-1: 32 x 64 full grid (logits)

// async 16B global->LDS (dest = wave-uniform base + lane*16)
__device__ inline void gload16(const bf16* g, bf16* l) {
    __builtin_amdgcn_global_load_lds((const __attribute__((address_space(1))) void*)g,
                                     (__attribute__((address_space(3))) void*)l, 16, 0, 0);
}

// ---------------- init: zero scalar accumulators + write labels ----------------
__global__ __launch_bounds__(256) void init_kernel(float* out) {
    int i = blockIdx.x * 256 + threadIdx.x;
    if (i < 2) out[i] = 0.f;
    if (i < NROW) out[(size_t)OUT_LABELS + i] = (float)(i & (BHALF - 1));
}

// ---------------- split fe into bf16 hi/lo + row norms ----------------
__global__ __launch_bounds__(256) void split_fe_kernel(const float* __restrict__ fe0,
                                                       const float* __restrict__ fe1,
                                                       bf16* __restrict__ feh,
                                                       bf16* __restrict__ fel,
                                                       float* __restrict__ norms) {
    int row = blockIdx.x, tid = threadIdx.x;
    const float* src = (row < BHALF) ? fe0 + (size_t)row * DFE
                                     : fe1 + (size_t)(row - BHALF) * DFE;
    float ss = 0.f;
#pragma unroll
    for (int pass = 0; pass < 2; ++pass) {
        int c = (pass * 256 + tid) * 4;
        float4 v = *(const float4*)(src + c);
        ss += v.x * v.x + v.y * v.y + v.z * v.z + v.w * v.w;
        bf16 h0 = (bf16)v.x, h1 = (bf16)v.y, h2 = (bf16)v.z, h3 = (bf16)v.w;
        bf16 l0 = (bf16)(v.x - (float)h0), l1 = (bf16)(v.y - (float)h1);
        bf16 l2 = (bf16)(v.z - (float)h2), l3 = (bf16)(v.w - (float)h3);
        bf16x4 hv = {h0, h1, h2, h3};
        bf16x4 lv = {l0, l1, l2, l3};
        *(bf16x4*)(feh + (size_t)row * DFE + c) = hv;
        *(bf16x4*)(fel + (size_t)row * DFE + c) = lv;
    }
#pragma unroll
    for (int off = 32; off; off >>= 1) ss += __shfl_down(ss, off);
    __shared__ float red[4];
    if ((tid & 63) == 0) red[tid >> 6] = ss;
    __syncthreads();
    if (tid == 0) norms[row] = red[0] + red[1] + red[2] + red[3];
}

// ---------------- l2-normalize p -> bf16 (HH-only logits path) ----------------
__global__ __launch_bounds__(256) void norm_split_p_kernel(const float* __restrict__ p0,
                                                           const float* __restrict__ p1,
                                                           bf16* __restrict__ oh) {
    int row = blockIdx.x, tid = threadIdx.x;
    const float* src = (row < BHALF) ? p0 + (size_t)row * DP
                                     : p1 + (size_t)(row - BHALF) * DP;
    float x = src[tid];
    float ss = x * x;
#pragma unroll
    for (int off = 32; off; off >>= 1) ss += __shfl_down(ss, off);
    __shared__ float red[4];
    if ((tid & 63) == 0) red[tid >> 6] = ss;
    __syncthreads();
    float tot = red[0] + red[1] + red[2] + red[3];
    float rn = 1.f / fmaxf(sqrtf(tot), 1e-12f);
    oh[(size_t)row * DP + tid] = (bf16)(x * rn);
}

// ---------------- BYOL main loss ----------------
__device__ inline float dot4(float4 a, float4 b) {
    return a.x * b.x + a.y * b.y + a.z * b.z + a.w * b.w;
}

__global__ __launch_bounds__(256) void byol_kernel(const float* __restrict__ p0,
                                                   const float* __restrict__ p1,
                                                   const float* __restrict__ z0,
                                                   const float* __restrict__ z1,
                                                   float* out) {
    int tid = threadIdx.x, wave = tid >> 6, lane = tid & 63;
    int row = blockIdx.x * 4 + wave;
    size_t base = (size_t)row * DP + lane * 4;
    float4 a0 = *(const float4*)(p0 + base);
    float4 b0 = *(const float4*)(z1 + base);
    float4 a1 = *(const float4*)(p1 + base);
    float4 b1 = *(const float4*)(z0 + base);
    float pp0 = dot4(a0, a0), zz0 = dot4(b0, b0), pz0 = dot4(a0, b0);
    float pp1 = dot4(a1, a1), zz1 = dot4(b1, b1), pz1 = dot4(a1, b1);
#pragma unroll
    for (int off = 32; off; off >>= 1) {
        pp0 += __shfl_down(pp0, off); zz0 += __shfl_down(zz0, off); pz0 += __shfl_down(pz0, off);
        pp1 += __shfl_down(pp1, off); zz1 += __shfl_down(zz1, off); pz1 += __shfl_down(pz1, off);
    }
    __shared__ float red[4];
    if (lane == 0) {
        float c0 = pz0 / (fmaxf(sqrtf(pp0), 1e-12f) * fmaxf(sqrtf(zz0), 1e-12f));
        float c1 = pz1 / (fmaxf(sqrtf(pp1), 1e-12f) * fmaxf(sqrtf(zz1), 1e-12f));
        red[wave] = (2.f - 2.f * c0) + (2.f - 2.f * c1);
    }
    __syncthreads();
    if (tid == 0) atomicAdd(out, (red[0] + red[1] + red[2] + red[3]) * (1.f / 4096.f));
}

// ---------------- online linear-probe CE loss ----------------
__global__ __launch_bounds__(256) void online_kernel(const float* __restrict__ cls0,
                                                     const float* __restrict__ cls1,
                                                     const int* __restrict__ labels,
                                                     float* out) {
    int tid = threadIdx.x, wave = tid >> 6, lane = tid & 63;
    int row = blockIdx.x * 4 + wave;
    const float* src = (row < BHALF) ? cls0 + (size_t)row * NCLS
                                     : cls1 + (size_t)(row - BHALF) * NCLS;
    int lbl = labels[row & (BHALF - 1)];
    float xs[16];
    float mx = -INFINITY;
#pragma unroll
    for (int j = 0; j < 16; ++j) {
        int c = lane + j * 64;
        xs[j] = (c < NCLS) ? src[c] : -INFINITY;
        mx = fmaxf(mx, xs[j]);
    }
#pragma unroll
    for (int off = 32; off; off >>= 1) mx = fmaxf(mx, __shfl_xor(mx, off));
    float se = 0.f;
#pragma unroll
    for (int j = 0; j < 16; ++j) se += expf(xs[j] - mx);
#pragma unroll
    for (int off = 32; off; off >>= 1) se += __shfl_xor(se, off);
    __shared__ float red[4];
    if (lane == 0) red[wave] = src[lbl] - mx - logf(se);
    __syncthreads();
    if (tid == 0) atomicAdd(out + 1, -(red[0] + red[1] + red[2] + red[3]) * (1.f / 8192.f));
}

// ---------------- merged 256x128-tile pipelined GEMM (mode0: d2, mode1: logits) ----------------
// 8 waves (WM=4 x WN=2), per-wave 64x64 output (4x4 frags of 16x16x32 bf16 MFMA).
// ONE phase per 64-wide K-tile: frags for tile t+1 are ds_read-issued BEFORE the MFMA
// cluster of tile t (register double-buffer), hiding LDS latency under MFMA.
// 2 barriers per K-tile; counted vmcnt(6) (never drained mid-loop).
// Staging runs 2 K-tiles ahead into the LDS buffer just vacated.
// XOR-swizzle: LDS[row][phys_grp] holds logical grp^(row&7) (verified layout).
__global__ __launch_bounds__(512, 2) void gemm_kernel(const bf16* __restrict__ Hp,
                                                      const bf16* __restrict__ Lp,
                                                      const bf16* __restrict__ OHp,
                                                      const float* __restrict__ norms,
                                                      float* __restrict__ d2,
                                                      float* __restrict__ outlog) {
    __shared__ bf16 sm[2][24576];  // per buf: A[256][64] @0, B[128][64] @16384 elts
    int tid = threadIdx.x, lane = tid & 63, wave = tid >> 6;
    int wr = wave >> 1, wc = wave & 1;
    int lrow = lane & 15, lquad = lane >> 4, r7 = lrow & 7, pg = lquad ^ r7;
    int rsub = lane >> 3, grp = lane & 7, lg = grp ^ rsub;

    int bid = blockIdx.x;
    int mode, tm, tn, ksh;
    const bf16 *Hmat, *Lmat;
    int Kd;
    if (bid < G0TILES) {
        mode = 0;
        int sw = (bid & 7) * (G0TILES / 8) + (bid >> 3);
        int i = 0;
        while ((i + 1) * (65 - (i + 1)) <= sw) ++i;  // prefix(i) = i*(65-i)
        tm = i;
        tn = 2 * i + (sw - i * (65 - i));
        Hmat = Hp; Lmat = Lp; Kd = DFE; ksh = 5;
    } else {
        mode = 1;
        int id = bid - G0TILES;
        int sw = (id & 7) * (G1TILES / 8) + (id >> 3);
        tm = sw & 31; tn = sw >> 5;
        Hmat = OHp; Lmat = OHp; Kd = DP; ksh = 2;
    }
    int NT = (mode == 0 ? 3 : 1) << ksh;  // 96 or 4 (always even)
    int kmask = (1 << ksh) - 1;
    int arow0 = tm * 256, brow0 = tn * 128;
    size_t delta = (size_t)(Lmat - Hmat);  // 0 in mode 1

    // per-wave staging base pointers (chunk-0 matrix; add delta for L chunks)
    const bf16* baseA[4];
    const bf16* baseB[2];
#pragma unroll
    for (int q = 0; q < 4; ++q)
        baseA[q] = Hmat + (size_t)(arow0 + q * 64 + wave * 8 + rsub) * Kd + lg * 8;
#pragma unroll
    for (int q = 0; q < 2; ++q)
        baseB[q] = Hmat + (size_t)(brow0 + q * 64 + wave * 8 + rsub) * Kd + lg * 8;

    // fragment LDS byte offsets within a buffer (ks=1 half is ^64)
    int aoff[4], boff[4];
#pragma unroll
    for (int t = 0; t < 4; ++t) {
        aoff[t] = (((t * 4 + wr) * 16 + lrow) * 64) * 2 + pg * 16;
        boff[t] = 32768 + (((t * 2 + wc) * 16 + lrow) * 64) * 2 + pg * 16;
    }
    const char* S0 = (const char*)sm[0];
    const char* S1 = (const char*)sm[1];

    f32x4 acc[4][4];
    f32x4 zz = {0.f, 0.f, 0.f, 0.f};
#pragma unroll
    for (int i = 0; i < 4; ++i)
#pragma unroll
        for (int j = 0; j < 4; ++j) acc[i][j] = zz;

#define STAGE(nt, B)                                                        \
    do {                                                                    \
        int ch_ = (nt) >> ksh;                                              \
        int k_ = ((nt) & kmask) << 6;                                       \
        size_t dA_ = (ch_ == 1) ? delta : 0;                                \
        size_t dB_ = (ch_ == 2) ? delta : 0;                                \
        _Pragma("unroll") for (int q = 0; q < 4; ++q)                       \
            gload16(baseA[q] + dA_ + k_, (B) + q * 4096 + wave * 512);      \
        _Pragma("unroll") for (int q = 0; q < 2; ++q)                       \
            gload16(baseB[q] + dB_ + k_, (B) + 16384 + q * 4096 + wave * 512); \
    } while (0)

#define READF(AF, BF, SB)                                                   \
    do {                                                                    \
        _Pragma("unroll") for (int t = 0; t < 4; ++t) {                     \
            AF[t][0] = *(const bf16x8*)((SB) + aoff[t]);                    \
            AF[t][1] = *(const bf16x8*)((SB) + (aoff[t] ^ 64));             \
        }                                                                   \
        _Pragma("unroll") for (int t = 0; t < 4; ++t) {                     \
            BF[t][0] = *(const bf16x8*)((SB) + boff[t]);                    \
            BF[t][1] = *(const bf16x8*)((SB) + (boff[t] ^ 64));             \
        }                                                                   \
    } while (0)

#define MFMAC(AF, BF)                                                       \
    do {                                                                    \
        __builtin_amdgcn_s_setprio(1);                                      \
        _Pragma("unroll") for (int i = 0; i < 4; ++i)                       \
            _Pragma("unroll") for (int j = 0; j < 4; ++j) {                 \
                acc[i][j] = __builtin_amdgcn_mfma_f32_16x16x32_bf16(AF[i][0], BF[j][0], acc[i][j], 0, 0, 0); \
                acc[i][j] = __builtin_amdgcn_mfma_f32_16x16x32_bf16(AF[i][1], BF[j][1], acc[i][j], 0, 0, 0); \
            }                                                               \
        __builtin_amdgcn_s_setprio(0);                                      \
    } while (0)

    bf16x8 af0[4][2], bf0[4][2], af1[4][2], bf1[4][2];

    // prologue: stage tiles 0 and 1 (12 vm-ops), wait tile0 (keep 6 in flight)
    STAGE(0, sm[0]);
    STAGE(1, sm[1]);
    asm volatile("s_waitcnt vmcnt(6)" ::: "memory");
    __builtin_amdgcn_s_barrier();
    __builtin_amdgcn_sched_barrier(0);
    READF(af0, bf0, S0);

    for (int t = 0; t < NT; t += 2) {
        // ---- even body: compute tile t (F0/buf0); prefetch F1 <- tile t+1 (buf1)
        asm volatile("s_waitcnt lgkmcnt(0)" ::: "memory");
        __builtin_amdgcn_sched_barrier(0);
        __builtin_amdgcn_s_barrier();  // all waves done reading buf0
        if (t + 2 < NT) {
            STAGE(t + 2, sm[0]);
            asm volatile("s_waitcnt vmcnt(6)" ::: "memory");  // tile t+1 landed
        } else {
            asm volatile("s_waitcnt vmcnt(0)" ::: "memory");
        }
        __builtin_amdgcn_s_barrier();  // buf1 visible to all waves
        __builtin_amdgcn_sched_barrier(0);
        READF(af1, bf1, S1);
        __builtin_amdgcn_sched_barrier(0);  // keep reads issued before MFMA
        MFMAC(af0, bf0);

        // ---- odd body: compute tile t+1 (F1/buf1); prefetch F0 <- tile t+2 (buf0)
        asm volatile("s_waitcnt lgkmcnt(0)" ::: "memory");
        __builtin_amdgcn_sched_barrier(0);
        __builtin_amdgcn_s_barrier();  // all waves done reading buf1
        if (t + 3 < NT) {
            STAGE(t + 3, sm[1]);
            asm volatile("s_waitcnt vmcnt(6)" ::: "memory");  // tile t+2 landed
        } else if (t + 2 < NT) {
            asm volatile("s_waitcnt vmcnt(0)" ::: "memory");
        }
        __builtin_amdgcn_s_barrier();  // buf0 visible to all waves
        if (t + 2 < NT) {
            __builtin_amdgcn_sched_barrier(0);
            READF(af0, bf0, S0);
            __builtin_amdgcn_sched_barrier(0);
        }
        MFMAC(af1, bf1);
    }

    // ---------------- epilogue ----------------
    if (mode == 0) {
#pragma unroll
        for (int i = 0; i < 4; ++i) {
#pragma unroll
            for (int e = 0; e < 4; ++e) {
                int grow = arow0 + (i * 4 + wr) * 16 + lquad * 4 + e;
                float na = norms[grow];
#pragma unroll
                for (int j = 0; j < 4; ++j) {
                    int gcol = tn * 128 + (j * 2 + wc) * 16 + lrow;
                    float v = na + norms[gcol] - 2.f * acc[i][j][e];
                    d2[(size_t)grow * NROW + gcol] = fmaxf(v, 0.f);
                }
            }
        }
    } else {
#pragma unroll
        for (int i = 0; i < 4; ++i) {
#pragma unroll
            for (int j = 0; j < 4; ++j) {
#pragma unroll
                for (int e = 0; e < 4; ++e) {
                    int r = arow0 + (i * 4 + wr) * 16 + lquad * 4 + e;
                    int c = tn * 128 + (j * 2 + wc) * 16 + lrow;
                    int oc = 0;
                    bool skip = false;
                    if (r < BHALF) {
                        if (c >= BHALF) oc = c - BHALF;           // l01 block
                        else if (c == r) skip = true;             // diag of l00
                        else oc = BHALF + (c < r ? c : c - 1);    // l00 nodiag
                    } else {
                        int rp = r - BHALF;
                        if (c < BHALF) oc = c;                    // l10 block
                        else {
                            int cp = c - BHALF;
                            if (cp == rp) skip = true;            // diag of l11
                            else oc = BHALF + (cp < rp ? cp : cp - 1);
                        }
                    }
                    if (!skip) outlog[(size_t)r * LOGITS_N + oc] = acc[i][j][e];
                }
            }
        }
    }
#undef STAGE
#undef READF
#undef MFMAC
}

// ---------------- mirror upper triangle of D2 into lower ----------------
__global__ __launch_bounds__(256) void mirror_kernel(float* __restrict__ d2) {
    int bj = blockIdx.x, bi = blockIdx.y;
    if (bi < bj) return;  // only lower-left (incl diagonal) blocks write
    __shared__ float t[32][33];
    int tx = threadIdx.x & 31, ty = threadIdx.x >> 5;  // 32 x 8
#pragma unroll
    for (int r = 0; r < 32; r += 8)
        t[r + ty][tx] = d2[(size_t)(bj * 32 + r + ty) * NROW + bi * 32 + tx];
    __syncthreads();
#pragma unroll
    for (int r = 0; r < 32; r += 8) {
        int gi = bi * 32 + r + ty, gj = bj * 32 + tx;
        if (gi > gj) d2[(size_t)gi * NROW + gj] = t[tx][r + ty];
    }
}

// ---------------- wave-per-row exact rank-32 / rank-512 select + LID ----------------
// 128 values/lane in VGPRs, no block barriers; common-prefix skip via AND/OR reduce.
__global__ __launch_bounds__(256) void select_kernel(const float* __restrict__ d2,
                                                     float* __restrict__ out) {
    int wave = threadIdx.x >> 6, lane = threadIdx.x & 63;
    int row = blockIdx.x * 4 + wave;
    const float4* drow4 = (const float4*)(d2 + (size_t)row * NROW);
    unsigned v[128];
    unsigned andv = 0xFFFFFFFFu, orv = 0u;
#pragma unroll
    for (int j = 0; j < 32; ++j) {
        int idx4 = j * 64 + lane;
        float4 f = drow4[idx4];
        int c0 = idx4 * 4;
        unsigned u0 = __float_as_uint(f.x), u1 = __float_as_uint(f.y);
        unsigned u2 = __float_as_uint(f.z), u3 = __float_as_uint(f.w);
        bool s0 = (c0 == row), s1 = (c0 + 1 == row), s2 = (c0 + 2 == row), s3 = (c0 + 3 == row);
        v[j * 4 + 0] = s0 ? 0xFFFFFFFFu : u0;
        v[j * 4 + 1] = s1 ? 0xFFFFFFFFu : u1;
        v[j * 4 + 2] = s2 ? 0xFFFFFFFFu : u2;
        v[j * 4 + 3] = s3 ? 0xFFFFFFFFu : u3;
        andv &= (s0 ? 0xFFFFFFFFu : u0); orv |= (s0 ? 0u : u0);
        andv &= (s1 ? 0xFFFFFFFFu : u1); orv |= (s1 ? 0u : u1);
        andv &= (s2 ? 0xFFFFFFFFu : u2); orv |= (s2 ? 0u : u2);
        andv &= (s3 ? 0xFFFFFFFFu : u3); orv |= (s3 ? 0u : u3);
    }
#pragma unroll
    for (int off = 32; off; off >>= 1) {
        andv &= __shfl_xor(andv, off);
        orv |= __shfl_xor(orv, off);
    }
    unsigned diff = andv ^ orv;
    int msb = 31 - __clz((int)(diff | 1u));
    unsigned common = (msb == 31) ? 0u : (andv & (0xFFFFFFFFu << (msb + 1)));
    unsigned p1 = common, p2 = common;
    for (int bit = msb; bit >= 0; --bit) {
        unsigned c1 = p1 | (1u << bit), c2 = p2 | (1u << bit);
        unsigned n1 = 0, n2 = 0;
#pragma unroll
        for (int j = 0; j < 128; ++j) { n1 += (v[j] < c1); n2 += (v[j] < c2); }
#pragma unroll
        for (int off = 32; off; off >>= 1) {
            n1 += __shfl_xor(n1, off);
            n2 += __shfl_xor(n2, off);
        }
        if (n1 < 32u) p1 = c1;
        if (n2 < 512u) p2 = c2;
    }
    float dk1 = sqrtf(__uint_as_float(p1));
    float dk2 = sqrtf(__uint_as_float(p2));
    float s1 = 0.f, s2 = 0.f;
#pragma unroll
    for (int j = 0; j < 128; ++j) {
        unsigned b = v[j];
        if (b < p2) {
            float d = sqrtf(__uint_as_float(b));
            s2 += logf(d / dk2 + 1e-12f);
            if (b < p1) s1 += logf(d / dk1 + 1e-12f);
        }
    }
#pragma unroll
    for (int off = 32; off; off >>= 1) {
        s1 += __shfl_xor(s1, off);
        s2 += __shfl_xor(s2, off);
    }
    if (lane == 0) {
        out[(size_t)OUT_LIDS32 + row] = -32.f / s1;
        out[(size_t)OUT_LIDS512 + row] = -512.f / s2;
    }
}

extern "C" void kernel_launch(void* const* d_in, const int* in_sizes, int n_in,
                              void* d_out, int out_size, void* d_ws, size_t ws_size,
                              hipStream_t stream) {
    const float* fe0 = (const float*)d_in[0];
    const float* fe1 = (const float*)d_in[1];
    const float* p0 = (const float*)d_in[2];
    const float* p1 = (const float*)d_in[3];
    const float* z0 = (const float*)d_in[4];
    const float* z1 = (const float*)d_in[5];
    const float* cls0 = (const float*)d_in[6];
    const float* cls1 = (const float*)d_in[7];
    const int* labels = (const int*)d_in[8];
    float* out = (float*)d_out;

    // workspace layout
    char* ws = (char*)d_ws;
    float* D2 = (float*)ws;                                        // 268435456 B
    bf16* FEH = (bf16*)(ws + 268435456UL);                         // 33554432 B
    bf16* FEL = (bf16*)(ws + 268435456UL + 33554432UL);            // 33554432 B
    bf16* OH = (bf16*)(ws + 268435456UL + 2 * 33554432UL);         // 4194304 B
    float* NORMS = (float*)(ws + 268435456UL + 2 * 33554432UL + 4194304UL);  // 32 KB

    init_kernel<<<32, 256, 0, stream>>>(out);
    split_fe_kernel<<<8192, 256, 0, stream>>>(fe0, fe1, FEH, FEL, NORMS);
    norm_split_p_kernel<<<8192, 256, 0, stream>>>(p0, p1, OH);
    byol_kernel<<<1024, 256, 0, stream>>>(p0, p1, z0, z1, out);
    online_kernel<<<2048, 256, 0, stream>>>(cls0, cls1, labels, out);
    // merged GEMM: blocks [0,1056) = d2 triangle tiles, [1056,3104) = logits tiles
    gemm_kernel<<<G0TILES + G1TILES, 512, 0, stream>>>(FEH, FEL, OH, NORMS, D2, out + OUT_LOGITS);
    mirror_kernel<<<dim3(256, 256), 256, 0, stream>>>(D2);
    select_kernel<<<2048, 256, 0, stream>>>(D2, out);
}